// Round 14
// baseline (65.872 us; speedup 1.0000x reference)
//
#include <hip/hip_runtime.h>
#include <stdint.h>

#define VOCAB     128000
#define BINS      4096                // 12-bit bins everywhere
#define BPR       2                   // threshold segments per row
#define CHUNK     (VOCAB / BPR)       // 64000 floats per segment
#define N4C       (CHUNK / 4)         // 16000 float4 per segment
#define NSAMP4    (N4C / 16)          // 1000 float4 sampled (every 16th 64B line)
#define TILES     16                  // filter tiles per row
#define TILE4     (VOCAB / 4 / TILES) // 2000 float4 per tile
#define TPBF      256                 // filter threads per block
#define STCAP     1024                // LDS staging entries per filter block
#define CAND_CAP  4096                // per-row candidate capacity
#define FILT_CAP  512                 // post-prune capacity in finalize
#define KEEP_CAP  128

typedef float nfloat4 __attribute__((ext_vector_type(4)));  // nontemporal stores

__device__ __forceinline__ uint32_t rotl32(uint32_t x, uint32_t r) {
    return (x << r) | (x >> (32u - r));
}

// monotone float -> uint transform (total order)
__device__ __forceinline__ uint32_t f2ord(float f) {
    uint32_t u = __float_as_uint(f);
    return (u & 0x80000000u) ? ~u : (u | 0x80000000u);
}

// Threefry-2x32, 20 rounds, key = (0, 42)  [jax.random.key(42)] — verified round 1
__device__ __forceinline__ void threefry_0_42(uint32_t x0, uint32_t x1,
                                              uint32_t& o0, uint32_t& o1) {
    const uint32_t k0 = 0u, k1 = 42u;
    const uint32_t k2 = 0x1BD11BDAu ^ k0 ^ k1;
#define TF_RND(R) { x0 += x1; x1 = rotl32(x1, (R)); x1 ^= x0; }
    x0 += k0; x1 += k1;
    TF_RND(13) TF_RND(15) TF_RND(26) TF_RND(6)
    x0 += k1; x1 += k2 + 1u;
    TF_RND(17) TF_RND(29) TF_RND(16) TF_RND(24)
    x0 += k2; x1 += k0 + 2u;
    TF_RND(13) TF_RND(15) TF_RND(26) TF_RND(6)
    x0 += k0; x1 += k1 + 3u;
    TF_RND(17) TF_RND(29) TF_RND(16) TF_RND(24)
    x0 += k1; x1 += k2 + 4u;
    TF_RND(13) TF_RND(15) TF_RND(26) TF_RND(6)
    x0 += k2; x1 += k0 + 5u;
#undef TF_RND
    o0 = x0; o1 = x1;
}

__device__ __forceinline__ float gumbel_at(uint64_t flat) {
    uint32_t o0, o1;
    threefry_0_42((uint32_t)(flat >> 32), (uint32_t)flat, o0, o1);
    uint32_t bits = o0 ^ o1;
    float f = __uint_as_float((bits >> 9) | 0x3F800000u) - 1.0f;
    float u = (f == 0.0f) ? 1.17549435e-38f : f;
    return -logf(-logf(u));
}

// ---------------------------------------------------------------------------
// KZ: bulk zero of d_out at the proper memory-bound shape. hipMemsetAsync's
// fill kernel measured only 1.6 TB/s (41 us) for this 65.5 MB buffer; a
// grid-stride nt-store kernel at 2048x256 should run at the ~6.5 TB/s
// write ceiling (R11-measured on the harness's 256 MB fill).
// ---------------------------------------------------------------------------
extern "C" __global__ __launch_bounds__(256)
void zero_kernel(float* __restrict__ p, int n) {
    const nfloat4 z4 = { 0.0f, 0.0f, 0.0f, 0.0f };
    const int n4 = n >> 2;
    const int stride = gridDim.x * blockDim.x;
    for (int i = blockIdx.x * blockDim.x + threadIdx.x; i < n4; i += stride)
        __builtin_nontemporal_store(z4, (nfloat4*)(p + 4 * (size_t)i));
    // scalar tail (n % 4)
    int t = (n4 << 2) + (int)(blockIdx.x * blockDim.x + threadIdx.x);
    if (blockIdx.x == 0 && t < n) p[t] = 0.0f;
}

// ---------------------------------------------------------------------------
// K0: per-(row,segment) threshold. Samples every 16th 64B line (all 16
// scalars), 12-bit LDS hist, local top-K bin -> tbins[]. Zeroes the per-row
// candidate counter. Subset sampling keeps the threshold conservative
// (>=K samples >= tbin => >=K real elements >= tbin => superset of top-K).
// ---------------------------------------------------------------------------
extern "C" __global__ __launch_bounds__(1024)
void hist_kernel(const float* __restrict__ logits,
                 const float* __restrict__ temp_p,
                 const int*   __restrict__ topk_p,
                 int* __restrict__ tbins,
                 int* __restrict__ counters,
                 int batch) {
    const int row = blockIdx.x / BPR;
    const int sub = blockIdx.x % BPR;
    const int c0  = sub * CHUNK;
    const int tid = threadIdx.x;

    const float rT = 1.0f / temp_p[0];
    const int   K  = topk_p[0];

    __shared__ int hist[BINS];
    __shared__ int s_grp[256];

    for (int i = tid; i < BINS; i += 1024) hist[i] = 0;
    __syncthreads();

    const float4* rowp = (const float4*)(logits + (size_t)row * VOCAB) + (c0 >> 2);

    // sampled lines: s -> line group g = s>>2 (line 16g), float4 idx = 64g + (s&3)
    for (int s = tid; s < NSAMP4; s += 1024) {
        int i4 = ((s >> 2) << 6) + (s & 3);
        float4 v = rowp[i4];
        atomicAdd(&hist[f2ord(v.x * rT) >> 20], 1);
        atomicAdd(&hist[f2ord(v.y * rT) >> 20], 1);
        atomicAdd(&hist[f2ord(v.z * rT) >> 20], 1);
        atomicAdd(&hist[f2ord(v.w * rT) >> 20], 1);
    }
    __syncthreads();

    if (tid < 256) {
        int s = 0;
        #pragma unroll
        for (int b = 0; b < 16; ++b) s += hist[tid * 16 + b];
        s_grp[tid] = s;
    }
    __syncthreads();
    if (tid == 0) {
        int cum = 0, g = 255;
        for (; g > 0; --g) {
            if (cum + s_grp[g] >= K) break;
            cum += s_grp[g];
        }
        int tb = g * 16;
        for (int b = g * 16 + 15; ; --b) {
            cum += hist[b];
            if (cum >= K || b == g * 16) { tb = b; break; }
        }
        tbins[row * BPR + sub] = tb;
        if (sub == 0) counters[row] = 0;
    }
}

// ---------------------------------------------------------------------------
// K1: READ-ONLY streaming filter. 2048 blocks x 256 threads (8/CU).
// Unconditional clamped loads (stay in flight), filter vs precomputed tbin,
// push to LDS staging (cheap DS atomics), then ONE global atomicAdd per
// block reserves a contiguous range (R11-proven: kills cross-XCD atomic
// contention).
// ---------------------------------------------------------------------------
extern "C" __global__ __launch_bounds__(TPBF)
void filter_kernel(const float* __restrict__ logits,
                   const float* __restrict__ temp_p,
                   const int*   __restrict__ tbins,
                   float* __restrict__ candV,
                   int*   __restrict__ candI,
                   int*   __restrict__ counters,
                   int batch, int cap) {
    const int bid = blockIdx.x;
    const int row = bid / TILES;
    const int t   = bid % TILES;
    const int tid = threadIdx.x;
    const int base4 = t * TILE4;

    __shared__ float stV[STCAP];
    __shared__ int   stI[STCAP];
    __shared__ int   s_cnt;
    __shared__ int   s_base;

    if (tid == 0) s_cnt = 0;
    __syncthreads();

    const float rT = 1.0f / temp_p[0];
    const uint32_t tbin = (uint32_t)tbins[row * BPR + (t >> 3)];  // 8 tiles/segment

    const float4* rowp = (const float4*)(logits + (size_t)row * VOCAB) + base4;

    int* ctr = &counters[row];
    float* cVrow = candV + (size_t)row * cap;
    int*   cIrow = candI + (size_t)row * cap;

    #pragma unroll
    for (int u = 0; u < 8; ++u) {
        int i = u * TPBF + tid;
        int ic = i < TILE4 ? i : TILE4 - 1;   // clamp: load stays unconditional
        float4 v = rowp[ic];
        if (i < TILE4) {
            float ss[4] = { v.x * rT, v.y * rT, v.z * rT, v.w * rT };
            int e = (base4 + i) * 4;
            #pragma unroll
            for (int c = 0; c < 4; ++c) {
                if ((f2ord(ss[c]) >> 20) >= tbin) {
                    int p = atomicAdd(&s_cnt, 1);
                    if (p < STCAP) { stV[p] = ss[c]; stI[p] = e + c; }
                    else {                            // rare overflow: direct push
                        int q = atomicAdd(ctr, 1);
                        if (q < cap) { cVrow[q] = ss[c]; cIrow[q] = e + c; }
                    }
                }
            }
        }
    }
    __syncthreads();

    const int staged = min(s_cnt, STCAP);
    if (tid == 0) s_base = atomicAdd(ctr, staged);     // ONE global atomic/block
    __syncthreads();
    const int base = s_base;
    for (int i = tid; i < staged; i += TPBF) {
        int dst = base + i;
        if (dst < cap) { cVrow[dst] = stV[i]; cIrow[dst] = stI[i]; }
    }
}

// ---------------------------------------------------------------------------
// K2: per-row finalize (proven). Candidates read from global (L2-hot, two
// passes: 12-bit hist, then filtered collect into LDS). Rank-sort survivors,
// verified serial top-k/top-p math with PARALLEL expf, Gumbel-argmax,
// scatter probs (buffer pre-zeroed by KZ) + token.
// ---------------------------------------------------------------------------
extern "C" __global__ __launch_bounds__(512)
void finalize_kernel(const float* __restrict__ topp_p,
                     const int*   __restrict__ topk_p,
                     const float* __restrict__ candV,
                     const int*   __restrict__ candI,
                     const int*   __restrict__ counters,
                     float* __restrict__ out,
                     int batch, int cap) {
    const int row  = blockIdx.x;
    const int tid  = threadIdx.x;
    const int nthr = blockDim.x;

    const float thresh = 1.0f - topp_p[0];
    const int   K      = topk_p[0];

    __shared__ uint32_t h2[BINS];
    __shared__ int      s_grp[256];
    __shared__ float    fV[FILT_CAP];
    __shared__ int      fI[FILT_CAP];
    __shared__ float    sV[FILT_CAP];
    __shared__ int      sI[FILT_CAP];
    __shared__ float    eArr[KEEP_CAP * 2];
    __shared__ float    s_gs[KEEP_CAP];
    __shared__ int      s_bstar, s_cnt2, s_Kp, s_M, s_token;
    __shared__ float    s_Z2;

    const int n = min(counters[row], cap);
    const float* cVrow = candV + (size_t)row * cap;
    const int*   cIrow = candI + (size_t)row * cap;
    for (int i = tid; i < BINS; i += nthr) h2[i] = 0u;
    if (tid == 0) s_cnt2 = 0;
    __syncthreads();

    // pass 1: exact 12-bit hist over candidates (global reads, L2-hot)
    for (int i = tid; i < n; i += nthr) atomicAdd(&h2[f2ord(cVrow[i]) >> 20], 1u);
    __syncthreads();
    if (tid < 256) {
        int s = 0;
        #pragma unroll
        for (int b = 0; b < 16; ++b) s += (int)h2[tid * 16 + b];
        s_grp[tid] = s;
    }
    __syncthreads();
    if (tid == 0) {
        int cum = 0, g = 255;
        for (; g > 0; --g) {
            if (cum + s_grp[g] >= K) break;
            cum += s_grp[g];
        }
        int tb = g * 16;
        for (int b = g * 16 + 15; ; --b) {
            cum += (int)h2[b];
            if (cum >= K || b == g * 16) { tb = b; break; }
        }
        s_bstar = tb;
    }
    __syncthreads();
    const uint32_t bstar = (uint32_t)s_bstar;

    // pass 2: collect survivors (bin >= bstar keeps all >= kth value w/ ties)
    for (int i = tid; i < n; i += nthr) {
        float v = cVrow[i];
        if ((f2ord(v) >> 20) >= bstar) {
            int p = atomicAdd(&s_cnt2, 1);
            if (p < FILT_CAP) { fV[p] = v; fI[p] = cIrow[i]; }
        }
    }
    __syncthreads();
    const int n2 = min(s_cnt2, FILT_CAP);

    // rank sort descending (unique total order via index tiebreak)
    for (int j = tid; j < n2; j += nthr) {
        float vj = fV[j]; int ij = fI[j];
        int r = 0;
        for (int l = 0; l < n2; ++l) {
            float vl = fV[l];
            r += (vl > vj) || (vl == vj && fI[l] < ij);
        }
        sV[r] = vj; sI[r] = ij;
    }
    __syncthreads();

    // Kp = top-k survivor count (ties at kth kept), then parallel expf
    if (tid == 0) {
        int Keff = min(K, n2);
        float kth = sV[Keff - 1];
        int Kp = Keff;
        while (Kp < n2 && sV[Kp] == kth) ++Kp;
        if (Kp > KEEP_CAP * 2) Kp = KEEP_CAP * 2;
        s_Kp = Kp;
    }
    __syncthreads();
    const int Kp = s_Kp;
    const float m = sV[0];
    for (int j = tid; j < Kp; j += nthr) eArr[j] = expf(sV[j] - m);
    __syncthreads();

    // serial part is adds/divides only (verified accumulation order)
    if (tid == 0) {
        float Z = 0.0f;
        for (int j = Kp - 1; j >= 0; --j) Z += eArr[j];
        float cum = 0.0f; int jcut = 0;
        for (int j = Kp - 1; j >= 0; --j) {
            cum += eArr[j] / Z;
            if (cum > thresh) { jcut = j; break; }
        }
        int M = jcut + 1;
        if (M > KEEP_CAP) M = KEEP_CAP;
        float Z2 = 0.0f;
        for (int j = 0; j < M; ++j) Z2 += eArr[j];
        s_M = M; s_Z2 = Z2;
    }
    __syncthreads();
    const int M = s_M;
    const float Z2 = s_Z2;

    if (tid < M) {
        uint64_t flat = (uint64_t)row * VOCAB + (uint32_t)sI[tid];
        s_gs[tid] = sV[tid] + gumbel_at(flat);
    }
    __syncthreads();
    if (tid == 0) {
        float bs = -__builtin_inff(); int bi = 0x7fffffff;
        for (int j = 0; j < M; ++j) {
            float s = s_gs[j]; int c = sI[j];
            if (s > bs || (s == bs && c < bi)) { bs = s; bi = c; }
        }
        s_token = bi;
    }
    __syncthreads();

    // probs row pre-zeroed by KZ — scatter kept probs + token
    for (int j = tid; j < M; j += nthr) {
        out[batch + (size_t)row * VOCAB + sI[j]] = eArr[j] / Z2;
    }
    if (tid == 0) out[row] = (float)s_token;
}

extern "C" void kernel_launch(void* const* d_in, const int* in_sizes, int n_in,
                              void* d_out, int out_size, void* d_ws, size_t ws_size,
                              hipStream_t stream) {
    (void)n_in;
    const float* logits = (const float*)d_in[0];
    const float* temp   = (const float*)d_in[1];
    const float* topp   = (const float*)d_in[2];
    const int*   topk   = (const int*)d_in[3];
    float* out = (float*)d_out;

    const int batch = in_sizes[0] / VOCAB;

    // ws layout: [counters: batch][tbins: batch*2][candV: batch*cap][candI: batch*cap]
    size_t hdr_bytes = ((size_t)batch * 3 * sizeof(int) + 255) & ~(size_t)255;
    int cap = CAND_CAP;
    if (ws_size > hdr_bytes) {
        size_t per_row = (ws_size - hdr_bytes) / ((size_t)batch * 8);
        if (per_row < (size_t)cap) cap = (int)per_row;
    }
    int*   counters = (int*)d_ws;
    int*   tbins    = counters + batch;
    float* candV    = (float*)((char*)d_ws + hdr_bytes);
    int*   candI    = (int*)(candV + (size_t)batch * cap);

    // custom bulk zero (hipMemsetAsync's fill ran at 1.6 TB/s for this size)
    zero_kernel<<<2048, 256, 0, stream>>>(out, out_size);

    hist_kernel<<<batch * BPR, 1024, 0, stream>>>(
        logits, temp, topk, tbins, counters, batch);

    filter_kernel<<<batch * TILES, TPBF, 0, stream>>>(
        logits, temp, tbins, candV, candI, counters, batch, cap);

    finalize_kernel<<<batch, 512, 0, stream>>>(
        topp, topk, candV, candI, counters, out, batch, cap);
}

// Round 15
// 53.247 us; speedup vs baseline: 1.2371x; 1.2371x over previous
//
#include <hip/hip_runtime.h>
#include <stdint.h>

#define VOCAB     128000
#define BINS      4096
#define BPR       2                 // blocks per row -> 256 blocks = 1 per CU
#define TPB1      1024              // threads per block (stage pass)
#define CHUNK     (VOCAB / BPR)     // 64000 floats per block
#define N4C       (CHUNK / 4)       // 16000 float4 per block
#define NSAMP4    (N4C / 8)         // 2000 sampled float4 (every 8th 64B line)
#define ZSPLIT    4096              // float4 zero-writes issued in pass 1
#define U2        4                 // pass-C load unroll
#define CAND_CAP  3072              // per-row candidate capacity (2 segments)
#define FILT_CAP  512               // post-prune capacity in finalize
#define KEEP_CAP  128

typedef float nfloat4 __attribute__((ext_vector_type(4)));  // nontemporal stores

__device__ __forceinline__ uint32_t rotl32(uint32_t x, uint32_t r) {
    return (x << r) | (x >> (32u - r));
}

// monotone float -> uint transform (total order)
__device__ __forceinline__ uint32_t f2ord(float f) {
    uint32_t u = __float_as_uint(f);
    return (u & 0x80000000u) ? ~u : (u | 0x80000000u);
}

// Threefry-2x32, 20 rounds, key = (0, 42)  [jax.random.key(42)] — verified round 1
__device__ __forceinline__ void threefry_0_42(uint32_t x0, uint32_t x1,
                                              uint32_t& o0, uint32_t& o1) {
    const uint32_t k0 = 0u, k1 = 42u;
    const uint32_t k2 = 0x1BD11BDAu ^ k0 ^ k1;
#define TF_RND(R) { x0 += x1; x1 = rotl32(x1, (R)); x1 ^= x0; }
    x0 += k0; x1 += k1;
    TF_RND(13) TF_RND(15) TF_RND(26) TF_RND(6)
    x0 += k1; x1 += k2 + 1u;
    TF_RND(17) TF_RND(29) TF_RND(16) TF_RND(24)
    x0 += k2; x1 += k0 + 2u;
    TF_RND(13) TF_RND(15) TF_RND(26) TF_RND(6)
    x0 += k0; x1 += k1 + 3u;
    TF_RND(17) TF_RND(29) TF_RND(16) TF_RND(24)
    x0 += k1; x1 += k2 + 4u;
    TF_RND(13) TF_RND(15) TF_RND(26) TF_RND(6)
    x0 += k2; x1 += k0 + 5u;
#undef TF_RND
    o0 = x0; o1 = x1;
}

__device__ __forceinline__ float gumbel_at(uint64_t flat) {
    uint32_t o0, o1;
    threefry_0_42((uint32_t)(flat >> 32), (uint32_t)flat, o0, o1);
    uint32_t bits = o0 ^ o1;
    float f = __uint_as_float((bits >> 9) | 0x3F800000u) - 1.0f;
    float u = (f == 0.0f) ? 1.17549435e-38f : f;
    return -logf(-logf(u));
}

// ---------------------------------------------------------------------------
// K1 (R9 structure + write-stream hiding): half-row per block (256 = 1/CU).
// pass 1: FIRST 4096 float4 zero-writes (25% of the d_out write budget,
//         ~1.6 TB/s cap => this phase is write-bound ~10us) issued
//         CONCURRENTLY with the sampled-line reads + DS-atomic histogram
//         (~4us on the separate LDS pipe — hidden).
// pass B: local top-K bin threshold from the sampled hist (subset sampling
//         keeps it conservative: >=K samples >= tbin => superset of top-K).
// pass C: full re-read (L3-hot) + filter into private segment (LDS counter,
//         R7/R9-proven) + remaining 75% of zero-writes.
// ---------------------------------------------------------------------------
extern "C" __global__ __launch_bounds__(TPB1)
void stage_kernel(const float* __restrict__ logits,
                  const float* __restrict__ temp_p,
                  const int*   __restrict__ topk_p,
                  float* __restrict__ out,
                  float* __restrict__ candV,
                  int*   __restrict__ candI,
                  int*   __restrict__ counters,
                  int batch, int cap) {
    const int row = blockIdx.x / BPR;
    const int sub = blockIdx.x % BPR;
    const int c0  = sub * CHUNK;
    const int tid = threadIdx.x;

    const float rT = 1.0f / temp_p[0];   // x*(1/T): validated (same absmax)
    const int   K  = topk_p[0];

    __shared__ int hist[BINS];
    __shared__ int s_grp[256];
    __shared__ int s_tbin;
    __shared__ int s_cnt;

    for (int i = tid; i < BINS; i += TPB1) hist[i] = 0;
    __syncthreads();

    const float4* rowp = (const float4*)(logits + (size_t)row * VOCAB) + (c0 >> 2);
    float4*       orow = (float4*)(out + batch + (size_t)row * VOCAB) + (c0 >> 2);
    const nfloat4 z4 = { 0.0f, 0.0f, 0.0f, 0.0f };

    // pass 1: sampled loads (clamped, stay in flight) + 4096 zero-writes + hist
    {
        int s0 = tid, s1 = tid + TPB1;
        int sc0 = s0 < NSAMP4 ? s0 : NSAMP4 - 1;
        int sc1 = s1 < NSAMP4 ? s1 : NSAMP4 - 1;
        int i40 = ((sc0 >> 2) << 5) + (sc0 & 3);
        int i41 = ((sc1 >> 2) << 5) + (sc1 & 3);
        float4 v0 = rowp[i40];
        float4 v1 = rowp[i41];
        #pragma unroll
        for (int k = 0; k < ZSPLIT / TPB1; ++k)
            __builtin_nontemporal_store(z4, (nfloat4*)&orow[k * TPB1 + tid]);
        if (s0 < NSAMP4) {
            atomicAdd(&hist[f2ord(v0.x * rT) >> 20], 1);
            atomicAdd(&hist[f2ord(v0.y * rT) >> 20], 1);
            atomicAdd(&hist[f2ord(v0.z * rT) >> 20], 1);
            atomicAdd(&hist[f2ord(v0.w * rT) >> 20], 1);
        }
        if (s1 < NSAMP4) {
            atomicAdd(&hist[f2ord(v1.x * rT) >> 20], 1);
            atomicAdd(&hist[f2ord(v1.y * rT) >> 20], 1);
            atomicAdd(&hist[f2ord(v1.z * rT) >> 20], 1);
            atomicAdd(&hist[f2ord(v1.w * rT) >> 20], 1);
        }
    }
    __syncthreads();

    // pass B: sampled top-K bin threshold (group sums + serial top-down scan)
    if (tid < 256) {
        int s = 0;
        #pragma unroll
        for (int b = 0; b < 16; ++b) s += hist[tid * 16 + b];
        s_grp[tid] = s;
    }
    __syncthreads();
    if (tid == 0) {
        int cum = 0, g = 255;
        for (; g > 0; --g) {
            if (cum + s_grp[g] >= K) break;
            cum += s_grp[g];
        }
        int tb = g * 16;
        for (int b = g * 16 + 15; ; --b) {
            cum += hist[b];
            if (cum >= K || b == g * 16) { tb = b; break; }
        }
        s_tbin = tb;
        s_cnt  = 0;
    }
    __syncthreads();
    const uint32_t tbin = (uint32_t)s_tbin;

    // pass C: full pass — read (L3-hot), filter+push to private segment,
    // remaining zero-writes (i >= ZSPLIT)
    const int cap2 = cap / 2;
    float* cVseg = candV + ((size_t)row * 2 + sub) * cap2;
    int*   cIseg = candI + ((size_t)row * 2 + sub) * cap2;
    for (int base = 0; base < N4C; base += TPB1 * U2) {
        float4 v[U2];
        int    idx[U2];
        #pragma unroll
        for (int u = 0; u < U2; ++u) {
            idx[u] = base + u * TPB1 + tid;
            if (idx[u] < N4C) v[u] = rowp[idx[u]];
        }
        #pragma unroll
        for (int u = 0; u < U2; ++u) {
            if (idx[u] < N4C) {
                float ss[4] = { v[u].x * rT, v[u].y * rT, v[u].z * rT, v[u].w * rT };
                int e = c0 + idx[u] * 4;
                #pragma unroll
                for (int c = 0; c < 4; ++c) {
                    if ((f2ord(ss[c]) >> 20) >= tbin) {
                        int p = atomicAdd(&s_cnt, 1);
                        if (p < cap2) { cVseg[p] = ss[c]; cIseg[p] = e + c; }
                    }
                }
                if (idx[u] >= ZSPLIT)
                    __builtin_nontemporal_store(z4, (nfloat4*)&orow[idx[u]]);
            }
        }
    }
    __syncthreads();
    if (tid == 0) counters[row * 2 + sub] = min(s_cnt, cap2);
}

// ---------------------------------------------------------------------------
// K2: per-row finalize (R9-proven). Load 2 segments, prune via exact
// 4096-bin hist (kth bin), rank-sort survivors, verified serial top-k/top-p
// math with PARALLEL expf, Gumbel-argmax, scatter probs + token.
// ---------------------------------------------------------------------------
extern "C" __global__ __launch_bounds__(512)
void finalize_kernel(const float* __restrict__ topp_p,
                     const int*   __restrict__ topk_p,
                     const float* __restrict__ candV,
                     const int*   __restrict__ candI,
                     const int*   __restrict__ counters,
                     float* __restrict__ out,
                     int batch, int cap) {
    const int row  = blockIdx.x;
    const int tid  = threadIdx.x;
    const int nthr = blockDim.x;

    const float thresh = 1.0f - topp_p[0];
    const int   K      = topk_p[0];

    __shared__ float    cV[CAND_CAP];
    __shared__ int      cI[CAND_CAP];
    __shared__ uint32_t h2[BINS];
    __shared__ int      s_grp[256];
    __shared__ float    fV[FILT_CAP];
    __shared__ int      fI[FILT_CAP];
    __shared__ float    sV[FILT_CAP];
    __shared__ int      sI[FILT_CAP];
    __shared__ float    eArr[KEEP_CAP * 2];
    __shared__ float    s_gs[KEEP_CAP];
    __shared__ int      s_bstar, s_cnt2, s_Kp, s_M, s_token;
    __shared__ float    s_Z2;

    const int cap2 = cap / 2;
    const int na = counters[row * 2];
    const int nb = counters[row * 2 + 1];
    const float* cVa = candV + ((size_t)row * 2) * cap2;
    const int*   cIa = candI + ((size_t)row * 2) * cap2;
    const float* cVb = candV + ((size_t)row * 2 + 1) * cap2;
    const int*   cIb = candI + ((size_t)row * 2 + 1) * cap2;
    for (int i = tid; i < na; i += nthr) { cV[i] = cVa[i]; cI[i] = cIa[i]; }
    for (int i = tid; i < nb; i += nthr) { cV[na + i] = cVb[i]; cI[na + i] = cIb[i]; }
    for (int i = tid; i < BINS; i += nthr) h2[i] = 0u;
    if (tid == 0) s_cnt2 = 0;
    __syncthreads();
    const int n = na + nb;

    // exact kth-value bin among candidates (superset of global top-K)
    for (int i = tid; i < n; i += nthr) atomicAdd(&h2[f2ord(cV[i]) >> 20], 1u);
    __syncthreads();
    if (tid < 256) {
        int s = 0;
        #pragma unroll
        for (int b = 0; b < 16; ++b) s += (int)h2[tid * 16 + b];
        s_grp[tid] = s;
    }
    __syncthreads();
    if (tid == 0) {
        int cum = 0, g = 255;
        for (; g > 0; --g) {
            if (cum + s_grp[g] >= K) break;
            cum += s_grp[g];
        }
        int tb = g * 16;
        for (int b = g * 16 + 15; ; --b) {
            cum += (int)h2[b];
            if (cum >= K || b == g * 16) { tb = b; break; }
        }
        s_bstar = tb;
    }
    __syncthreads();
    const uint32_t bstar = (uint32_t)s_bstar;

    // filter to bin >= bstar (keeps all >= kth value, incl. ties)
    for (int i = tid; i < n; i += nthr) {
        if ((f2ord(cV[i]) >> 20) >= bstar) {
            int p = atomicAdd(&s_cnt2, 1);
            if (p < FILT_CAP) { fV[p] = cV[i]; fI[p] = cI[i]; }
        }
    }
    __syncthreads();
    const int n2 = min(s_cnt2, FILT_CAP);

    // rank sort descending (unique total order via index tiebreak)
    for (int j = tid; j < n2; j += nthr) {
        float vj = fV[j]; int ij = fI[j];
        int r = 0;
        for (int l = 0; l < n2; ++l) {
            float vl = fV[l];
            r += (vl > vj) || (vl == vj && fI[l] < ij);
        }
        sV[r] = vj; sI[r] = ij;
    }
    __syncthreads();

    // Kp = top-k survivor count (ties at kth kept), then parallel expf
    if (tid == 0) {
        int Keff = min(K, n2);
        float kth = sV[Keff - 1];
        int Kp = Keff;
        while (Kp < n2 && sV[Kp] == kth) ++Kp;
        if (Kp > KEEP_CAP * 2) Kp = KEEP_CAP * 2;
        s_Kp = Kp;
    }
    __syncthreads();
    const int Kp = s_Kp;
    const float m = sV[0];
    for (int j = tid; j < Kp; j += nthr) eArr[j] = expf(sV[j] - m);
    __syncthreads();

    // serial part is adds/divides only (verified accumulation order)
    if (tid == 0) {
        float Z = 0.0f;
        for (int j = Kp - 1; j >= 0; --j) Z += eArr[j];
        float cum = 0.0f; int jcut = 0;
        for (int j = Kp - 1; j >= 0; --j) {
            cum += eArr[j] / Z;
            if (cum > thresh) { jcut = j; break; }
        }
        int M = jcut + 1;
        if (M > KEEP_CAP) M = KEEP_CAP;
        float Z2 = 0.0f;
        for (int j = 0; j < M; ++j) Z2 += eArr[j];
        s_M = M; s_Z2 = Z2;
    }
    __syncthreads();
    const int M = s_M;
    const float Z2 = s_Z2;

    if (tid < M) {
        uint64_t flat = (uint64_t)row * VOCAB + (uint32_t)sI[tid];
        s_gs[tid] = sV[tid] + gumbel_at(flat);
    }
    __syncthreads();
    if (tid == 0) {
        float bs = -__builtin_inff(); int bi = 0x7fffffff;
        for (int j = 0; j < M; ++j) {
            float s = s_gs[j]; int c = sI[j];
            if (s > bs || (s == bs && c < bi)) { bs = s; bi = c; }
        }
        s_token = bi;
    }
    __syncthreads();

    // probs row already zeroed by K1 — scatter kept probs + token
    for (int j = tid; j < M; j += nthr) {
        out[batch + (size_t)row * VOCAB + sI[j]] = eArr[j] / Z2;
    }
    if (tid == 0) out[row] = (float)s_token;
}

extern "C" void kernel_launch(void* const* d_in, const int* in_sizes, int n_in,
                              void* d_out, int out_size, void* d_ws, size_t ws_size,
                              hipStream_t stream) {
    (void)n_in; (void)out_size;
    const float* logits = (const float*)d_in[0];
    const float* temp   = (const float*)d_in[1];
    const float* topp   = (const float*)d_in[2];
    const int*   topk   = (const int*)d_in[3];
    float* out = (float*)d_out;

    const int batch = in_sizes[0] / VOCAB;

    // ws layout: [counters: batch*2 ints][candV: batch*cap floats][candI: batch*cap ints]
    size_t ctr_bytes = ((size_t)batch * BPR * sizeof(int) + 255) & ~(size_t)255;
    int cap = CAND_CAP;
    if (ws_size > ctr_bytes) {
        size_t per_row = (ws_size - ctr_bytes) / ((size_t)batch * 8);
        if (per_row < (size_t)cap) cap = (int)(per_row & ~(size_t)1);
    }
    int*   counters = (int*)d_ws;
    float* candV    = (float*)((char*)d_ws + ctr_bytes);
    int*   candI    = (int*)(candV + (size_t)batch * cap);

    stage_kernel<<<batch * BPR, TPB1, 0, stream>>>(
        logits, temp, topk, out, candV, candI, counters, batch, cap);

    finalize_kernel<<<batch, 512, 0, stream>>>(
        topp, topk, candV, candI, counters, out, batch, cap);
}